// Round 8
// baseline (1379.287 us; speedup 1.0000x reference)
//
#include <hip/hip_runtime.h>

#define NNODE 16384
#define IN_F  256
#define OUT_F 128
#define ROWS  4      // one row per wave, 4 waves per block
#define MAXNB 256    // neighbor-list capacity (mean ~33, max ~60)

typedef float vfloat4 __attribute__((ext_vector_type(4)));  // NT builtins need native vec

// Block = 256 threads = 4 waves; wave w owns row row0+w. Fused single kernel.
// Phase A+B INTERLEAVED: per 8-float4 chunk of the A-row, issue next chunk's
// NT loads, PROC current chunk into the LDS index list, then immediately
// gather the H rows discovered so far (watermark m -> s_cnt). The wave's
// gather latency is covered by its own outstanding A-loads, so the HBM pipe
// never drains during the gather phase (the R4..R7 kernels serialized these).
// Per-wave private list => no barriers; same-wave LDS ops are ordered.
// Phase C: out = agg @ W^T via broadcast ds_read_b128 + float4 W loads.
__global__ __launch_bounds__(256, 4) void gcn_fused_kernel(
    const float* __restrict__ A,
    const float* __restrict__ H,
    const float* __restrict__ W,
    float* __restrict__ out)
{
    __shared__ int   s_cnt[ROWS];
    __shared__ int   s_idx[ROWS][MAXNB];
    __shared__ float s_agg[ROWS][IN_F];
    __shared__ float s_part[OUT_F][ROWS + 1];   // +1 pad: kill bank conflicts

    const int t    = threadIdx.x;
    const int wave = t >> 6;
    const int lane = t & 63;
    const int row0 = blockIdx.x * ROWS;

    if (t < ROWS) s_cnt[t] = 0;
    __syncthreads();

    const vfloat4* A4 = reinterpret_cast<const vfloat4*>(
        A + (size_t)(row0 + wave) * NNODE);
    const float4* H4 = reinterpret_cast<const float4*>(H);

#define PROC(v, kk)                                                              \
    {                                                                            \
        int j = ((kk) * 64 + lane) * 4;                                          \
        if ((v).x != 0.f) { int p = atomicAdd(&s_cnt[wave], 1); if (p < MAXNB) s_idx[wave][p] = j;     } \
        if ((v).y != 0.f) { int p = atomicAdd(&s_cnt[wave], 1); if (p < MAXNB) s_idx[wave][p] = j + 1; } \
        if ((v).z != 0.f) { int p = atomicAdd(&s_cnt[wave], 1); if (p < MAXNB) s_idx[wave][p] = j + 2; } \
        if ((v).w != 0.f) { int p = atomicAdd(&s_cnt[wave], 1); if (p < MAXNB) s_idx[wave][p] = j + 3; } \
    }

    float4 g0 = {0.f, 0.f, 0.f, 0.f}, g1 = g0;
    int m = 0;                                     // gather watermark

    {
        vfloat4 cur[8], nxt[8];
        #pragma unroll
        for (int i = 0; i < 8; ++i)
            cur[i] = __builtin_nontemporal_load(&A4[i * 64 + lane]);

        #pragma unroll
        for (int b = 0; b < 8; ++b) {              // 8 chunks of 8 float4/lane
            if (b < 7) {
                #pragma unroll
                for (int i = 0; i < 8; ++i)
                    nxt[i] = __builtin_nontemporal_load(
                        &A4[((b + 1) * 8 + i) * 64 + lane]);
            }
            #pragma unroll
            for (int i = 0; i < 8; ++i)
                PROC(cur[i], b * 8 + i)

            // gather hits discovered so far; A-loads for chunk b+1 in flight
            int cl = s_cnt[wave];
            if (cl > MAXNB) cl = MAXNB;
            for (; m + 2 <= cl; m += 2) {
                int j0 = s_idx[wave][m], j1 = s_idx[wave][m + 1];
                float4 v0 = H4[(size_t)j0 * 64 + lane];
                float4 v1 = H4[(size_t)j1 * 64 + lane];
                g0.x += v0.x; g0.y += v0.y; g0.z += v0.z; g0.w += v0.w;
                g1.x += v1.x; g1.y += v1.y; g1.z += v1.z; g1.w += v1.w;
            }

            if (b < 7) {
                #pragma unroll
                for (int i = 0; i < 8; ++i) cur[i] = nxt[i];
            }
        }
    }
#undef PROC

    // ---- tail: remaining unconsumed hits (0 or 1 typically) ----
    const int cnt = s_cnt[wave];
    int cl = cnt < MAXNB ? cnt : MAXNB;
    for (; m < cl; ++m) {
        int j = s_idx[wave][m];
        float4 v = H4[(size_t)j * 64 + lane];
        g0.x += v.x; g0.y += v.y; g0.z += v.z; g0.w += v.w;
    }

    const float inv = 1.f / (float)(cnt + 1);
    float4 agg;
    agg.x = (g0.x + g1.x) * inv;
    agg.y = (g0.y + g1.y) * inv;
    agg.z = (g0.z + g1.z) * inv;
    agg.w = (g0.w + g1.w) * inv;
    *reinterpret_cast<float4*>(&s_agg[wave][lane * 4]) = agg;
    __syncthreads();

    // ---- Phase C: out[row, o] = dot(agg[row,:], W[o,:]) ----
    const int o    = t & (OUT_F - 1);
    const int half = t >> 7;                       // 0 or 1
    float acc[ROWS] = {0.f, 0.f, 0.f, 0.f};

    const float4* W4 = reinterpret_cast<const float4*>(
        W + (size_t)o * IN_F + half * (IN_F / 2));
    for (int kk = 0; kk < IN_F / 2 / 4; ++kk) {    // 32 iterations
        float4 wv = W4[kk];
        const int c = half * (IN_F / 2) + kk * 4;
        #pragma unroll
        for (int r = 0; r < ROWS; ++r) {
            float4 g = *reinterpret_cast<const float4*>(&s_agg[r][c]);  // broadcast
            acc[r] += wv.x * g.x + wv.y * g.y + wv.z * g.z + wv.w * g.w;
        }
    }

    if (half == 1) {
        #pragma unroll
        for (int r = 0; r < ROWS; ++r) s_part[o][r] = acc[r];
    }
    __syncthreads();
    if (half == 0) {
        #pragma unroll
        for (int r = 0; r < ROWS; ++r)
            __builtin_nontemporal_store(acc[r] + s_part[o][r],
                                        &out[(size_t)(row0 + r) * OUT_F + o]);
    }
}

extern "C" void kernel_launch(void* const* d_in, const int* in_sizes, int n_in,
                              void* d_out, int out_size, void* d_ws, size_t ws_size,
                              hipStream_t stream) {
    const float* A = (const float*)d_in[0];   // [N, N]
    const float* H = (const float*)d_in[1];   // [N, IN_F]
    const float* W = (const float*)d_in[2];   // [OUT_F, IN_F]
    float* out = (float*)d_out;               // [N, OUT_F]

    dim3 grid(NNODE / ROWS);                  // 4096 blocks
    dim3 block(256);
    gcn_fused_kernel<<<grid, block, 0, stream>>>(A, H, W, out);
}